// Round 5
// baseline (3859.433 us; speedup 1.0000x reference)
//
#include <hip/hip_runtime.h>
#include <cstdint>

typedef __attribute__((ext_vector_type(8))) short bf16x8;
typedef __attribute__((ext_vector_type(4))) float f32x4;
typedef unsigned short u16;

// ---------- bf16 helpers (round-to-nearest-even) ----------
__device__ __forceinline__ u16 f2bf(float x) {
  unsigned u = __builtin_bit_cast(unsigned, x);
  return (u16)((u + 0x7FFFu + ((u >> 16) & 1u)) >> 16);
}
__device__ __forceinline__ float bf2f(u16 h) {
  unsigned u = ((unsigned)h) << 16;
  return __builtin_bit_cast(float, u);
}
__device__ __forceinline__ f32x4 mfma16(bf16x8 a, bf16x8 b, f32x4 c) {
  return __builtin_amdgcn_mfma_f32_16x16x32_bf16(a, b, c, 0, 0, 0);
}

// Packed MFMA-fragment index for Mat[r][k]: frag=(r>>4)*KC+(k>>5), lane=((k&31)>>3)<<4|(r&15), j=k&7
__device__ __forceinline__ size_t pidx(int r, int k, int KC) {
  return ((size_t)((r >> 4) * KC + (k >> 5))) * 512 +
         (size_t)(((((k & 31) >> 3) << 4) | (r & 15)) * 8) + (size_t)(k & 7);
}
// plane-triple interleaved gate row: orig (p, e) -> ((e>>4)*3+p)*16 + (e&15)
__device__ __forceinline__ int rowperm(int p, int e) {
  return (((e >> 4) * 3 + p) << 4) + (e & 15);
}

// ---------- setup kernels ----------
__global__ void k_round(const float* __restrict__ whh, const float* __restrict__ wun,
                        u16* __restrict__ whhp, u16* __restrict__ wunp) {
  int i = blockIdx.x * 256 + threadIdx.x, st = 1024 * 256;
  for (int j = i; j < 3072 * 1024; j += st) {
    int r = j >> 10, k = j & 1023;
    int p = r >> 10, e = r & 1023;
    whhp[pidx(rowperm(p, e), k, 32)] = f2bf(whh[j]);
  }
  for (int j = i; j < 256 * 1024; j += st) {
    int r = j >> 10, k = j & 1023;
    wunp[pidx(r, k, 32)] = f2bf(wun[j]);
  }
}

__global__ void k_hinit(const float* __restrict__ c, u16* __restrict__ hhi,
                        u16* __restrict__ hlo) {
  int i = blockIdx.x * 256 + threadIdx.x;  // 262144
  int b = i >> 10, e = i & 1023;
  float v = c[i];
  u16 hi = f2bf(v);
  size_t o = pidx(b, e, 32);
  hhi[o] = hi;
  hlo[o] = f2bf(v - bf2f(hi));
}

__global__ void k_zero(unsigned* __restrict__ bar) { bar[threadIdx.x] = 0u; }

// W_comb = W_ih @ W_tok -> packed bf16 frags (KC=8), plane-interleaved rows
__global__ void k_wcomb(const float* __restrict__ wih, const float* __restrict__ wtok,
                        u16* __restrict__ wcb) {
  __shared__ float la[64][33];
  __shared__ float lb[32][65];
  int i0 = blockIdx.x << 6, j0 = blockIdx.y << 6;
  int tid = threadIdx.x;
  int ty = tid >> 4, tx = tid & 15;
  float acc[4][4] = {};
  for (int k0 = 0; k0 < 1024; k0 += 32) {
    __syncthreads();
#pragma unroll
    for (int i = 0; i < 8; ++i) {
      int r = (tid >> 5) + i * 8, cc = tid & 31;
      la[r][cc] = wih[(size_t)(i0 + r) * 1024 + k0 + cc];
    }
#pragma unroll
    for (int i = 0; i < 8; ++i) {
      int idx = i * 256 + tid;
      int r = idx >> 6, cc = idx & 63;
      lb[r][cc] = wtok[(size_t)(k0 + r) * 256 + j0 + cc];
    }
    __syncthreads();
#pragma unroll
    for (int kk = 0; kk < 32; ++kk) {
      float av[4], bv[4];
#pragma unroll
      for (int ii = 0; ii < 4; ++ii) av[ii] = la[ty * 4 + ii][kk];
#pragma unroll
      for (int jj = 0; jj < 4; ++jj) bv[jj] = lb[kk][tx * 4 + jj];
#pragma unroll
      for (int ii = 0; ii < 4; ++ii)
#pragma unroll
        for (int jj = 0; jj < 4; ++jj) acc[ii][jj] += av[ii] * bv[jj];
    }
  }
#pragma unroll
  for (int ii = 0; ii < 4; ++ii)
#pragma unroll
    for (int jj = 0; jj < 4; ++jj) {
      int r = i0 + ty * 4 + ii;
      int p = r >> 10, e = r & 1023;
      wcb[pidx(rowperm(p, e), j0 + tx * 4 + jj, 8)] = f2bf(acc[ii][jj]);
    }
}

__global__ void k_bcomb(const float* __restrict__ wih, const float* __restrict__ btok,
                        const float* __restrict__ bih, float* __restrict__ bc) {
  __shared__ float red[256];
  int j = blockIdx.x, t = threadIdx.x;
  float s = 0.f;
  for (int e = t; e < 1024; e += 256) s += wih[(size_t)j * 1024 + e] * btok[e];
  red[t] = s;
  __syncthreads();
  for (int off = 128; off > 0; off >>= 1) {
    if (t < off) red[t] += red[t + off];
    __syncthreads();
  }
  if (t == 0) bc[j] = red[0] + bih[j];
}

// x packed per step-slice (KC=8): slice k holds x[:, :, 127+k] for k in [1,128)
__global__ void k_xprep(const float* __restrict__ x, u16* __restrict__ xhi,
                        u16* __restrict__ xlo) {
  __shared__ float t[64][129];
  int bid = blockIdx.x;
  int b = bid >> 2, d0 = (bid & 3) << 6;
  int tid = threadIdx.x;
#pragma unroll
  for (int i = 0; i < 32; ++i) {
    int idx = i * 256 + tid;
    int dd = idx >> 7, tt = idx & 127;
    t[dd][tt] = x[(size_t)b * 65536 + (size_t)(d0 + dd) * 256 + 128 + tt];
  }
  __syncthreads();
#pragma unroll
  for (int i = 0; i < 32; ++i) {
    int idx = i * 256 + tid;
    int dd = idx & 63, kk = idx >> 6;
    if (kk < 127) {
      float v = t[dd][kk];
      u16 hi = f2bf(v);
      size_t o = (size_t)(kk + 1) * 65536 + pidx(b, d0 + dd, 8);
      xhi[o] = hi;
      xlo[o] = f2bf(v - bf2f(hi));
    }
  }
}

// ---------- persistent recurrence, group-local barrier ----------
// 256 WGs x 512 thr. WG (mt=bid>>6, eb=bid&63): rows [mt*64,+64), gate-col block eb (16 e).
// W slice LDS-resident. Groups of 64 WGs (same mt) sync independently.
__launch_bounds__(512, 1)
__global__ void k_gru(u16* __restrict__ hhi, u16* __restrict__ hlo,
                      const u16* __restrict__ xhi, const u16* __restrict__ xlo,
                      const u16* __restrict__ whp, const u16* __restrict__ wcp,
                      const float* __restrict__ bih, const float* __restrict__ bcb,
                      const float* __restrict__ bhh, u16* __restrict__ ys,
                      unsigned* __restrict__ bar) {
  __shared__ __align__(16) u16 lwh[3][32][512];   // 96KB
  __shared__ __align__(16) u16 lwc[3][8][512];    // 24KB
  __shared__ __align__(16) float red[4][4][256];  // 16KB
  __shared__ __align__(16) u16 sth[64][16];       // 2KB
  __shared__ __align__(16) u16 stl[64][16];       // 2KB

  int bid = blockIdx.x;
  int mt = bid >> 6, eb = bid & 63;
  int tid = threadIdx.x;
  int w = tid >> 6, lane = tid & 63, l15 = lane & 15, l4 = lane >> 4;
  int ws = w & 1, mw = w >> 1;
  int rg = mt * 4 + mw;  // 16-row group this wave loads

  // W slice -> LDS
  for (int p = 0; p < 3; ++p) {
    const u16* s1 = whp + ((size_t)(eb * 3 + p) * 32) * 512;
#pragma unroll
    for (int i = 0; i < 4; ++i)
      *(uint4*)&lwh[p][0][i * 4096 + tid * 8] = *(const uint4*)(s1 + i * 4096 + tid * 8);
    const u16* s2 = wcp + ((size_t)(eb * 3 + p) * 8) * 512;
    *(uint4*)&lwc[p][0][tid * 8] = *(const uint4*)(s2 + tid * 8);
  }
  __syncthreads();

  int e = (eb << 4) + l15;
  float bhr = bhh[e], bhz = bhh[1024 + e], bhn = bhh[2048 + e];
  float bAr = bih[e] + bhr, bAz = bih[1024 + e] + bhz, bAn = bih[2048 + e];
  float bBr = bcb[e] + bhr, bBz = bcb[1024 + e] + bhz, bBn = bcb[2048 + e];

  unsigned* cnt_p = bar + mt * 64;
  unsigned* gen_p = bar + mt * 64 + 32;

  const size_t hrow = (size_t)rg * 16384 + (size_t)(lane * 8);  // rg*32*512
  const size_t xrow = (size_t)rg * 4096 + (size_t)(lane * 8);   // rg*8*512

  for (int k = 0; k < 128; ++k) {
    int cur = k & 1, nxt = cur ^ 1;
    const u16* Hh = hhi + (size_t)cur * 262144 + hrow;
    const u16* Hl = hlo + (size_t)cur * 262144 + hrow;

    f32x4 aRh{}, aRl{}, aZh{}, aZl{}, aNh{}, aNl{}, aXh{}, aXl{};
#pragma unroll
    for (int kc = 0; kc < 16; ++kc) {
      int kk = ws * 16 + kc;
      bf16x8 ah = *(const bf16x8*)(Hh + (size_t)kk * 512);
      bf16x8 al = *(const bf16x8*)(Hl + (size_t)kk * 512);
      bf16x8 b0 = *(const bf16x8*)&lwh[0][kk][lane * 8];
      bf16x8 b1 = *(const bf16x8*)&lwh[1][kk][lane * 8];
      bf16x8 b2 = *(const bf16x8*)&lwh[2][kk][lane * 8];
      aRh = mfma16(ah, b0, aRh); aRl = mfma16(al, b0, aRl);
      aZh = mfma16(ah, b1, aZh); aZl = mfma16(al, b1, aZl);
      aNh = mfma16(ah, b2, aNh); aNl = mfma16(al, b2, aNl);
    }
    if (k > 0) {
      const u16* Xh = xhi + (size_t)k * 65536 + xrow;
      const u16* Xl = xlo + (size_t)k * 65536 + xrow;
#pragma unroll
      for (int kc = 0; kc < 4; ++kc) {
        int kk = ws * 4 + kc;
        bf16x8 ah = *(const bf16x8*)(Xh + (size_t)kk * 512);
        bf16x8 al = *(const bf16x8*)(Xl + (size_t)kk * 512);
        bf16x8 b0 = *(const bf16x8*)&lwc[0][kk][lane * 8];
        bf16x8 b1 = *(const bf16x8*)&lwc[1][kk][lane * 8];
        bf16x8 b2 = *(const bf16x8*)&lwc[2][kk][lane * 8];
        aRh = mfma16(ah, b0, aRh); aRl = mfma16(al, b0, aRl);
        aZh = mfma16(ah, b1, aZh); aZl = mfma16(al, b1, aZl);
        aXh = mfma16(ah, b2, aXh); aXl = mfma16(al, b2, aXl);
      }
    }

    if (ws == 1) {
      *(f32x4*)&red[mw][0][lane * 4] = aRh + aRl;
      *(f32x4*)&red[mw][1][lane * 4] = aZh + aZl;
      *(f32x4*)&red[mw][2][lane * 4] = aNh + aNl;
      *(f32x4*)&red[mw][3][lane * 4] = aXh + aXl;
    }
    __syncthreads();
    if (ws == 0) {
      f32x4 vR = aRh + aRl + *(const f32x4*)&red[mw][0][lane * 4];
      f32x4 vZ = aZh + aZl + *(const f32x4*)&red[mw][1][lane * 4];
      f32x4 vN = aNh + aNl + *(const f32x4*)&red[mw][2][lane * 4];
      f32x4 vX = aXh + aXl + *(const f32x4*)&red[mw][3][lane * 4];
      float bir = k ? bBr : bAr, biz = k ? bBz : bAz, bin = k ? bBn : bAn;
      int lanepart = ((eb & 1) * 2 + (l15 >> 3)) * 16;
#pragma unroll
      for (int j = 0; j < 4; ++j) {
        int b15 = l4 * 4 + j;
        size_t ho = ((size_t)(rg * 32 + (eb >> 1))) * 512 +
                    (size_t)((lanepart + b15) * 8) + (size_t)(l15 & 7);
        float hold = bf2f(hhi[(size_t)cur * 262144 + ho]) +
                     bf2f(hlo[(size_t)cur * 262144 + ho]);
        float gr = vR[j] + bir;
        float gz = vZ[j] + biz;
        float gh = vN[j] + bhn;
        float gx = vX[j] + bin;
        float r = 1.f / (1.f + __expf(-gr));
        float z = 1.f / (1.f + __expf(-gz));
        float n = 1.f - 2.f / (1.f + __expf(2.f * (gx + r * gh)));
        float h = (1.f - z) * n + z * hold;
        u16 hi = f2bf(h);
        int row_rel = mw * 16 + b15;
        sth[row_rel][l15] = hi;
        stl[row_rel][l15] = f2bf(h - bf2f(hi));
      }
    }
    __syncthreads();

    if (tid < 256) {
      int c = tid & 127, row_rel = c >> 1, oct = c & 1;
      int frag = (mt * 4 + (row_rel >> 4)) * 32 + (eb >> 1);
      int inl = ((eb & 1) * 2 + oct) * 16 + (row_rel & 15);
      size_t off = (size_t)frag * 512 + (size_t)(inl * 8);
      uint4 v = (tid < 128) ? *(const uint4*)&sth[row_rel][oct * 8]
                            : *(const uint4*)&stl[row_rel][oct * 8];
      u16* dst = ((tid < 128) ? hhi : hlo) + (size_t)nxt * 262144;
      *(uint4*)(dst + off) = v;
    } else if (tid < 384) {
      int c = tid - 256, row_rel = c >> 1, oct = c & 1;
      int b = mt * 64 + row_rel;
      size_t fragrg = (size_t)(b * 8 + (k >> 4));
      size_t off = (fragrg * 32 + (size_t)(eb >> 1)) * 512 +
                   (size_t)((((eb & 1) * 2 + oct) * 16 + (k & 15)) * 8);
      *(uint4*)(ys + off) = *(const uint4*)&sth[row_rel][oct * 8];
    }

    if (k == 127) break;

    // group barrier (64 WGs sharing mt), monotonic epoch
    __syncthreads();  // drain all waves' stores (vmcnt) before arrival
    if (tid == 0) {
      __threadfence();  // make our h/ys stores agent-visible (L2 writeback)
      unsigned t = __hip_atomic_fetch_add(cnt_p, 1u, __ATOMIC_RELAXED,
                                          __HIP_MEMORY_SCOPE_AGENT);
      unsigned tgt = (unsigned)(k + 1) * 64u;
      if (t == tgt - 1u) {
        __hip_atomic_store(gen_p, (unsigned)(k + 1), __ATOMIC_RELEASE,
                           __HIP_MEMORY_SCOPE_AGENT);
      } else {
        while (__hip_atomic_load(gen_p, __ATOMIC_ACQUIRE,
                                 __HIP_MEMORY_SCOPE_AGENT) < (unsigned)(k + 1)) {
          __builtin_amdgcn_s_sleep(1);
        }
      }
      __threadfence();  // acquire side: invalidate stale L1/L2 lines
    }
    __syncthreads();
  }
}

// ---------- untokenizer: packed ys (A) x packed wun (B, LDS) -> out[b][d][kk] ----------
__launch_bounds__(256, 1)
__global__ void k_untok2(const u16* __restrict__ ysp, const u16* __restrict__ wunp,
                         const float* __restrict__ bun, float* __restrict__ out) {
  __shared__ __align__(16) u16 lwb[4][32][512];  // 128KB: d-slice B frags
  __shared__ float st[64][66];                   // staged output
  int bid = blockIdx.x;
  int nt4 = bid & 3, mtile = bid >> 2;
  int d0 = nt4 << 6;
  int row0 = mtile << 6;
  int b = mtile >> 1, kk0 = (mtile & 1) << 6;
  int tid = threadIdx.x, w = tid >> 6, lane = tid & 63, l15 = lane & 15, l4 = lane >> 4;

  {
    const u16* src = wunp + ((size_t)(d0 >> 4)) * 32 * 512;
    u16* dst = &lwb[0][0][0];
#pragma unroll
    for (int i = 0; i < 32; ++i) {
      int o = i * 2048 + tid * 8;
      *(uint4*)(dst + o) = *(const uint4*)(src + o);
    }
  }
  __syncthreads();

  int rg = (row0 >> 4) + w;
  const u16* A = ysp + ((size_t)rg * 32) * 512 + lane * 8;
  f32x4 acc[4] = {};
#pragma unroll 4
  for (int kc = 0; kc < 32; ++kc) {
    bf16x8 a = *(const bf16x8*)(A + (size_t)kc * 512);
#pragma unroll
    for (int nt = 0; nt < 4; ++nt) {
      bf16x8 bb = *(const bf16x8*)(&lwb[nt][kc][0] + lane * 8);
      acc[nt] = mfma16(a, bb, acc[nt]);
    }
  }
#pragma unroll
  for (int nt = 0; nt < 4; ++nt)
#pragma unroll
    for (int j = 0; j < 4; ++j)
      st[w * 16 + l4 * 4 + j][nt * 16 + l15] = acc[nt][j];
  __syncthreads();

  int d_rel = tid >> 2, c4 = tid & 3;
  float bv = bun[d0 + d_rel];
  float* orow = out + (size_t)b * 32768 + (size_t)(d0 + d_rel) * 128 + kk0;
#pragma unroll
  for (int rep = 0; rep < 4; ++rep) {
    int kb = (c4 * 4 + rep) * 4;
    float4 v = {st[kb][d_rel] + bv, st[kb + 1][d_rel] + bv,
                st[kb + 2][d_rel] + bv, st[kb + 3][d_rel] + bv};
    *(float4*)(orow + kb) = v;
  }
}

// ---------- launch ----------
extern "C" void kernel_launch(void* const* d_in, const int* in_sizes, int n_in,
                              void* d_out, int out_size, void* d_ws, size_t ws_size,
                              hipStream_t stream) {
  const float* c_in = (const float*)d_in[0];
  const float* x_in = (const float*)d_in[2];
  const float* Wih  = (const float*)d_in[3];
  const float* Whh  = (const float*)d_in[4];
  const float* bih  = (const float*)d_in[5];
  const float* bhh  = (const float*)d_in[6];
  const float* Wtok = (const float*)d_in[7];
  const float* btok = (const float*)d_in[8];
  const float* Wun  = (const float*)d_in[9];
  const float* bun  = (const float*)d_in[10];
  float* out = (float*)d_out;
  char* ws = (char*)d_ws;

  const size_t OW_HH = 0;                     // u16 packed [6144 frags][512]
  const size_t OW_C  = 6291456;               // u16 packed [1536 frags][512]
  const size_t OW_UN = 7864320;               // u16 packed [512 frags][512]
  const size_t OBC   = 8388608;               // f32 [3072]
  const size_t OXHI  = 8400896;               // u16 [128][65536]
  const size_t OXLO  = 25178112;
  const size_t OHHI  = 41955328;              // u16 [2][262144]
  const size_t OHLO  = 43003904;
  const size_t OYS   = 44052480;              // u16 packed [65536 frags][512]
  const size_t OBAR  = 111161344;             // u32 [256] barrier state
  const size_t NEED  = 111162368;
  if (ws_size < NEED) return;

  u16* whh_p = (u16*)(ws + OW_HH);
  u16* wc_p  = (u16*)(ws + OW_C);
  u16* wun_p = (u16*)(ws + OW_UN);
  float* bc  = (float*)(ws + OBC);
  u16* xhi   = (u16*)(ws + OXHI);
  u16* xlo   = (u16*)(ws + OXLO);
  u16* hhi   = (u16*)(ws + OHHI);
  u16* hlo   = (u16*)(ws + OHLO);
  u16* ys    = (u16*)(ws + OYS);
  unsigned* bar = (unsigned*)(ws + OBAR);

  k_round<<<1024, 256, 0, stream>>>(Whh, Wun, whh_p, wun_p);
  k_wcomb<<<dim3(48, 4), 256, 0, stream>>>(Wih, Wtok, wc_p);
  k_bcomb<<<3072, 256, 0, stream>>>(Wih, btok, bih, bc);
  k_xprep<<<1024, 256, 0, stream>>>(x_in, xhi, xlo);
  k_hinit<<<1024, 256, 0, stream>>>(c_in, hhi, hlo);
  k_zero<<<1, 256, 0, stream>>>(bar);

  {
    u16* hhi_l = hhi;
    u16* hlo_l = hlo;
    const u16* xhi_l = xhi;
    const u16* xlo_l = xlo;
    const u16* whp_l = whh_p;
    const u16* wcp_l = wc_p;
    const float* bih_l = bih;
    const float* bc_l = bc;
    const float* bhh_l = bhh;
    u16* ys_l = ys;
    unsigned* bar_l = bar;
    void* args[] = {&hhi_l, &hlo_l, &xhi_l, &xlo_l, &whp_l, &wcp_l,
                    &bih_l, &bc_l, &bhh_l, &ys_l, &bar_l};
    hipLaunchCooperativeKernel((const void*)k_gru, dim3(256), dim3(512), args, 0, stream);
  }

  k_untok2<<<2048, 256, 0, stream>>>(ys, wun_p, bun, out);
}

// Round 6
// 1321.378 us; speedup vs baseline: 2.9208x; 2.9208x over previous
//
#include <hip/hip_runtime.h>
#include <cstdint>

typedef __attribute__((ext_vector_type(8))) short bf16x8;
typedef __attribute__((ext_vector_type(4))) float f32x4;
typedef unsigned short u16;
typedef unsigned long long u64;

// ---------- bf16 helpers (round-to-nearest-even) ----------
__device__ __forceinline__ u16 f2bf(float x) {
  unsigned u = __builtin_bit_cast(unsigned, x);
  return (u16)((u + 0x7FFFu + ((u >> 16) & 1u)) >> 16);
}
__device__ __forceinline__ float bf2f(u16 h) {
  unsigned u = ((unsigned)h) << 16;
  return __builtin_bit_cast(float, u);
}
__device__ __forceinline__ f32x4 mfma16(bf16x8 a, bf16x8 b, f32x4 c) {
  return __builtin_amdgcn_mfma_f32_16x16x32_bf16(a, b, c, 0, 0, 0);
}

// Coherent (agent-scope, relaxed) 16B load/store as 2x b64 atomics: sc1 path,
// write-through / cache-bypassing -> no L2 flush needed for cross-XCD exchange.
__device__ __forceinline__ bf16x8 ld_coh8(const u16* p) {
  u64 a = __hip_atomic_load((const u64*)p, __ATOMIC_RELAXED, __HIP_MEMORY_SCOPE_AGENT);
  u64 b = __hip_atomic_load((const u64*)(p + 4), __ATOMIC_RELAXED, __HIP_MEMORY_SCOPE_AGENT);
  ulonglong2 t;
  t.x = a;
  t.y = b;
  return __builtin_bit_cast(bf16x8, t);
}
__device__ __forceinline__ void st_coh16(u16* p, uint4 v) {
  ulonglong2 t = __builtin_bit_cast(ulonglong2, v);
  __hip_atomic_store((u64*)p, t.x, __ATOMIC_RELAXED, __HIP_MEMORY_SCOPE_AGENT);
  __hip_atomic_store((u64*)(p + 4), t.y, __ATOMIC_RELAXED, __HIP_MEMORY_SCOPE_AGENT);
}

// Packed MFMA-fragment index for Mat[r][k]: frag=(r>>4)*KC+(k>>5), lane=((k&31)>>3)<<4|(r&15), j=k&7
__device__ __forceinline__ size_t pidx(int r, int k, int KC) {
  return ((size_t)((r >> 4) * KC + (k >> 5))) * 512 +
         (size_t)(((((k & 31) >> 3) << 4) | (r & 15)) * 8) + (size_t)(k & 7);
}
// plane-triple interleaved gate row: orig (p, e) -> ((e>>4)*3+p)*16 + (e&15)
__device__ __forceinline__ int rowperm(int p, int e) {
  return (((e >> 4) * 3 + p) << 4) + (e & 15);
}

// ---------- setup kernels ----------
__global__ void k_round(const float* __restrict__ whh, const float* __restrict__ wun,
                        u16* __restrict__ whhp, u16* __restrict__ wunp) {
  int i = blockIdx.x * 256 + threadIdx.x, st = 1024 * 256;
  for (int j = i; j < 3072 * 1024; j += st) {
    int r = j >> 10, k = j & 1023;
    int p = r >> 10, e = r & 1023;
    whhp[pidx(rowperm(p, e), k, 32)] = f2bf(whh[j]);
  }
  for (int j = i; j < 256 * 1024; j += st) {
    int r = j >> 10, k = j & 1023;
    wunp[pidx(r, k, 32)] = f2bf(wun[j]);
  }
}

__global__ void k_hinit(const float* __restrict__ c, u16* __restrict__ hhi,
                        u16* __restrict__ hlo) {
  int i = blockIdx.x * 256 + threadIdx.x;  // 262144
  int b = i >> 10, e = i & 1023;
  float v = c[i];
  u16 hi = f2bf(v);
  size_t o = pidx(b, e, 32);
  hhi[o] = hi;
  hlo[o] = f2bf(v - bf2f(hi));
}

__global__ void k_zero(unsigned* __restrict__ bar) { bar[threadIdx.x] = 0u; }

// W_comb = W_ih @ W_tok -> packed bf16 frags (KC=8), plane-interleaved rows
__global__ void k_wcomb(const float* __restrict__ wih, const float* __restrict__ wtok,
                        u16* __restrict__ wcb) {
  __shared__ float la[64][33];
  __shared__ float lb[32][65];
  int i0 = blockIdx.x << 6, j0 = blockIdx.y << 6;
  int tid = threadIdx.x;
  int ty = tid >> 4, tx = tid & 15;
  float acc[4][4] = {};
  for (int k0 = 0; k0 < 1024; k0 += 32) {
    __syncthreads();
#pragma unroll
    for (int i = 0; i < 8; ++i) {
      int r = (tid >> 5) + i * 8, cc = tid & 31;
      la[r][cc] = wih[(size_t)(i0 + r) * 1024 + k0 + cc];
    }
#pragma unroll
    for (int i = 0; i < 8; ++i) {
      int idx = i * 256 + tid;
      int r = idx >> 6, cc = idx & 63;
      lb[r][cc] = wtok[(size_t)(k0 + r) * 256 + j0 + cc];
    }
    __syncthreads();
#pragma unroll
    for (int kk = 0; kk < 32; ++kk) {
      float av[4], bv[4];
#pragma unroll
      for (int ii = 0; ii < 4; ++ii) av[ii] = la[ty * 4 + ii][kk];
#pragma unroll
      for (int jj = 0; jj < 4; ++jj) bv[jj] = lb[kk][tx * 4 + jj];
#pragma unroll
      for (int ii = 0; ii < 4; ++ii)
#pragma unroll
        for (int jj = 0; jj < 4; ++jj) acc[ii][jj] += av[ii] * bv[jj];
    }
  }
#pragma unroll
  for (int ii = 0; ii < 4; ++ii)
#pragma unroll
    for (int jj = 0; jj < 4; ++jj) {
      int r = i0 + ty * 4 + ii;
      int p = r >> 10, e = r & 1023;
      wcb[pidx(rowperm(p, e), j0 + tx * 4 + jj, 8)] = f2bf(acc[ii][jj]);
    }
}

__global__ void k_bcomb(const float* __restrict__ wih, const float* __restrict__ btok,
                        const float* __restrict__ bih, float* __restrict__ bc) {
  __shared__ float red[256];
  int j = blockIdx.x, t = threadIdx.x;
  float s = 0.f;
  for (int e = t; e < 1024; e += 256) s += wih[(size_t)j * 1024 + e] * btok[e];
  red[t] = s;
  __syncthreads();
  for (int off = 128; off > 0; off >>= 1) {
    if (t < off) red[t] += red[t + off];
    __syncthreads();
  }
  if (t == 0) bc[j] = red[0] + bih[j];
}

// x packed per step-slice (KC=8): slice k holds x[:, :, 127+k] for k in [1,128)
__global__ void k_xprep(const float* __restrict__ x, u16* __restrict__ xhi,
                        u16* __restrict__ xlo) {
  __shared__ float t[64][129];
  int bid = blockIdx.x;
  int b = bid >> 2, d0 = (bid & 3) << 6;
  int tid = threadIdx.x;
#pragma unroll
  for (int i = 0; i < 32; ++i) {
    int idx = i * 256 + tid;
    int dd = idx >> 7, tt = idx & 127;
    t[dd][tt] = x[(size_t)b * 65536 + (size_t)(d0 + dd) * 256 + 128 + tt];
  }
  __syncthreads();
#pragma unroll
  for (int i = 0; i < 32; ++i) {
    int idx = i * 256 + tid;
    int dd = idx & 63, kk = idx >> 6;
    if (kk < 127) {
      float v = t[dd][kk];
      u16 hi = f2bf(v);
      size_t o = (size_t)(kk + 1) * 65536 + pidx(b, d0 + dd, 8);
      xhi[o] = hi;
      xlo[o] = f2bf(v - bf2f(hi));
    }
  }
}

// ---------- persistent recurrence, fence-free coherent h exchange ----------
// 256 WGs x 512 thr. WG (mt=bid>>6, eb=bid&63): rows [mt*64,+64), gate-col block eb (16 e).
// W LDS-resident. h via relaxed agent-scope atomics (sc1). Group (64 WGs per mt) barrier.
__launch_bounds__(512, 1)
__global__ void k_gru2(u16* __restrict__ hhi, u16* __restrict__ hlo,
                       const u16* __restrict__ xhi, const u16* __restrict__ xlo,
                       const u16* __restrict__ whp, const u16* __restrict__ wcp,
                       const float* __restrict__ bih, const float* __restrict__ bcb,
                       const float* __restrict__ bhh, u16* __restrict__ ys,
                       unsigned* __restrict__ bar) {
  __shared__ __align__(16) u16 lwh[3][32][512];   // 96KB
  __shared__ __align__(16) u16 lwc[3][8][512];    // 24KB
  __shared__ __align__(16) float red[4][4][256];  // 16KB
  __shared__ __align__(16) u16 sth[64][16];       // 2KB
  __shared__ __align__(16) u16 stl[64][16];       // 2KB
  __shared__ u16 hold_h[64][34];                  // 4.25KB
  __shared__ u16 hold_l[64][34];                  // 4.25KB

  int bid = blockIdx.x;
  int mt = bid >> 6, eb = bid & 63;
  int tid = threadIdx.x;
  int w = tid >> 6, lane = tid & 63, l15 = lane & 15, l4 = lane >> 4;
  int ws = w & 1, mw = w >> 1;
  int rg = mt * 4 + mw;  // 16-row frag group this wave handles

  // W slice -> LDS (plain loads; read-only data)
  for (int p = 0; p < 3; ++p) {
    const u16* s1 = whp + ((size_t)(eb * 3 + p) * 32) * 512;
#pragma unroll
    for (int i = 0; i < 4; ++i)
      *(uint4*)&lwh[p][0][i * 4096 + tid * 8] = *(const uint4*)(s1 + i * 4096 + tid * 8);
    const u16* s2 = wcp + ((size_t)(eb * 3 + p) * 8) * 512;
    *(uint4*)&lwc[p][0][tid * 8] = *(const uint4*)(s2 + tid * 8);
  }
  __syncthreads();

  int e = (eb << 4) + l15;
  float bhr = bhh[e], bhz = bhh[1024 + e], bhn = bhh[2048 + e];
  float bAr = bih[e] + bhr, bAz = bih[1024 + e] + bhz, bAn = bih[2048 + e];
  float bBr = bcb[e] + bhr, bBz = bcb[1024 + e] + bhz, bBn = bcb[2048 + e];

  unsigned* cnt_p = bar + mt * 64;
  unsigned* gen_p = bar + mt * 64 + 32;

  const size_t hrow = (size_t)rg * 16384 + (size_t)(lane * 8);  // rg*32*512
  const size_t xrow = (size_t)rg * 4096 + (size_t)(lane * 8);   // rg*8*512
  int hold_kc = eb >> 1;

  for (int k = 0; k < 128; ++k) {
    int cur = k & 1, nxt = cur ^ 1;

    f32x4 aRh{}, aRl{}, aZh{}, aZl{}, aNh{}, aNl{}, aXh{}, aXl{};

    // ---- x-part FIRST (no h dependency): overlaps the barrier wait ----
    if (k > 0) {
      const u16* Xh = xhi + (size_t)k * 65536 + xrow;
      const u16* Xl = xlo + (size_t)k * 65536 + xrow;
#pragma unroll
      for (int kc = 0; kc < 4; ++kc) {
        int kk = ws * 4 + kc;
        bf16x8 ah = *(const bf16x8*)(Xh + (size_t)kk * 512);
        bf16x8 al = *(const bf16x8*)(Xl + (size_t)kk * 512);
        bf16x8 b0 = *(const bf16x8*)&lwc[0][kk][lane * 8];
        bf16x8 b1 = *(const bf16x8*)&lwc[1][kk][lane * 8];
        bf16x8 b2 = *(const bf16x8*)&lwc[2][kk][lane * 8];
        aRh = mfma16(ah, b0, aRh); aRl = mfma16(al, b0, aRl);
        aZh = mfma16(ah, b1, aZh); aZl = mfma16(al, b1, aZl);
        aXh = mfma16(ah, b2, aXh); aXl = mfma16(al, b2, aXl);
      }
      // ---- group barrier wait: h of epoch k ready (relaxed polls, no cache ops) ----
      if (tid == 0) {
        while (__hip_atomic_load(gen_p, __ATOMIC_RELAXED, __HIP_MEMORY_SCOPE_AGENT) <
               (unsigned)k) {
          __builtin_amdgcn_s_sleep(2);
        }
      }
      __syncthreads();
    }

    // ---- h-part (coherent loads) ----
    const u16* Hh = hhi + (size_t)cur * 262144 + hrow;
    const u16* Hl = hlo + (size_t)cur * 262144 + hrow;
#pragma unroll
    for (int kc = 0; kc < 16; ++kc) {
      int kk = ws * 16 + kc;
      bf16x8 ah = ld_coh8(Hh + (size_t)kk * 512);
      bf16x8 al = ld_coh8(Hl + (size_t)kk * 512);
      bf16x8 b0 = *(const bf16x8*)&lwh[0][kk][lane * 8];
      bf16x8 b1 = *(const bf16x8*)&lwh[1][kk][lane * 8];
      bf16x8 b2 = *(const bf16x8*)&lwh[2][kk][lane * 8];
      aRh = mfma16(ah, b0, aRh); aRl = mfma16(al, b0, aRl);
      aZh = mfma16(ah, b1, aZh); aZl = mfma16(al, b1, aZl);
      aNh = mfma16(ah, b2, aNh); aNl = mfma16(al, b2, aNl);
    }

    // ---- hold stash: ws0 waves fetch the h_old frag this WG's epilogue needs ----
    if (ws == 0) {
      bf16x8 hh = ld_coh8(hhi + (size_t)cur * 262144 + (size_t)rg * 16384 +
                          (size_t)hold_kc * 512 + lane * 8);
      bf16x8 hl = ld_coh8(hlo + (size_t)cur * 262144 + (size_t)rg * 16384 +
                          (size_t)hold_kc * 512 + lane * 8);
      int r15 = lane & 15, oct = lane >> 4;
#pragma unroll
      for (int j = 0; j < 8; ++j) {
        hold_h[mw * 16 + r15][oct * 8 + j] = (u16)hh[j];
        hold_l[mw * 16 + r15][oct * 8 + j] = (u16)hl[j];
      }
    }

    if (ws == 1) {
      *(f32x4*)&red[mw][0][lane * 4] = aRh + aRl;
      *(f32x4*)&red[mw][1][lane * 4] = aZh + aZl;
      *(f32x4*)&red[mw][2][lane * 4] = aNh + aNl;
      *(f32x4*)&red[mw][3][lane * 4] = aXh + aXl;
    }
    __syncthreads();
    if (ws == 0) {
      f32x4 vR = aRh + aRl + *(const f32x4*)&red[mw][0][lane * 4];
      f32x4 vZ = aZh + aZl + *(const f32x4*)&red[mw][1][lane * 4];
      f32x4 vN = aNh + aNl + *(const f32x4*)&red[mw][2][lane * 4];
      f32x4 vX = aXh + aXl + *(const f32x4*)&red[mw][3][lane * 4];
      float bir = k ? bBr : bAr, biz = k ? bBz : bAz, bin = k ? bBn : bAn;
      int kwf = (eb & 1) * 16 + l15;
#pragma unroll
      for (int j = 0; j < 4; ++j) {
        int b15 = l4 * 4 + j;
        int row_rel = mw * 16 + b15;
        float hold = bf2f(hold_h[row_rel][kwf]) + bf2f(hold_l[row_rel][kwf]);
        float gr = vR[j] + bir;
        float gz = vZ[j] + biz;
        float gh = vN[j] + bhn;
        float gx = vX[j] + bin;
        float r = 1.f / (1.f + __expf(-gr));
        float z = 1.f / (1.f + __expf(-gz));
        float n = 1.f - 2.f / (1.f + __expf(2.f * (gx + r * gh)));
        float h = (1.f - z) * n + z * hold;
        u16 hi = f2bf(h);
        sth[row_rel][l15] = hi;
        stl[row_rel][l15] = f2bf(h - bf2f(hi));
      }
    }
    __syncthreads();

    // ---- stores: h (coherent write-through), ys (plain; consumed after kernel) ----
    if (tid < 256) {
      int c = tid & 127, row_rel = c >> 1, oct = c & 1;
      int frag = (mt * 4 + (row_rel >> 4)) * 32 + (eb >> 1);
      int inl = ((eb & 1) * 2 + oct) * 16 + (row_rel & 15);
      size_t off = (size_t)frag * 512 + (size_t)(inl * 8);
      uint4 v = (tid < 128) ? *(const uint4*)&sth[row_rel][oct * 8]
                            : *(const uint4*)&stl[row_rel][oct * 8];
      u16* dst = ((tid < 128) ? hhi : hlo) + (size_t)nxt * 262144;
      st_coh16(dst + off, v);
    } else if (tid < 384) {
      int c = tid - 256, row_rel = c >> 1, oct = c & 1;
      int b = mt * 64 + row_rel;
      size_t fragrg = (size_t)(b * 8 + (k >> 4));
      size_t off = (fragrg * 32 + (size_t)(eb >> 1)) * 512 +
                   (size_t)((((eb & 1) * 2 + oct) * 16 + (k & 15)) * 8);
      *(uint4*)(ys + off) = *(const uint4*)&sth[row_rel][oct * 8];
    }

    if (k < 127) {
      // drain stores (syncthreads emits s_waitcnt vmcnt(0) before s_barrier),
      // then relaxed arrive; last arriver bumps the group epoch.
      __syncthreads();
      if (tid == 0) {
        unsigned t = __hip_atomic_fetch_add(cnt_p, 1u, __ATOMIC_RELAXED,
                                            __HIP_MEMORY_SCOPE_AGENT);
        if (t == (unsigned)(k + 1) * 64u - 1u)
          __hip_atomic_store(gen_p, (unsigned)(k + 1), __ATOMIC_RELAXED,
                             __HIP_MEMORY_SCOPE_AGENT);
      }
    }
  }
}

// ---------- untokenizer: packed frags, direct full-line float4 stores, no big LDS ----------
__launch_bounds__(256, 4)
__global__ void k_untok3(const u16* __restrict__ ysp, const u16* __restrict__ wunp,
                         const float* __restrict__ bun, float* __restrict__ out) {
  int bid = blockIdx.x;  // 1024 = 512 mtiles x 2 d-halves
  int mtile = bid >> 1, dh = bid & 1;
  int b = mtile >> 1, kk0 = (mtile & 1) << 6;
  int w = threadIdx.x >> 6, lane = threadIdx.x & 63, l15 = lane & 15, l4 = lane >> 4;
  int rg = mtile * 4 + w;
  const u16* A = ysp + (size_t)rg * 16384 + (size_t)(lane * 8);
  f32x4 acc[8] = {};
  float bv[8];
#pragma unroll
  for (int nt = 0; nt < 8; ++nt) bv[nt] = bun[dh * 128 + nt * 16 + l15];
#pragma unroll 4
  for (int kc = 0; kc < 32; ++kc) {
    bf16x8 a = *(const bf16x8*)(A + (size_t)kc * 512);
#pragma unroll
    for (int nt = 0; nt < 8; ++nt) {
      const u16* B = wunp + ((size_t)((dh * 8 + nt) * 32 + kc)) * 512 + (size_t)(lane * 8);
      acc[nt] = mfma16(a, *(const bf16x8*)B, acc[nt]);
    }
  }
#pragma unroll
  for (int nt = 0; nt < 8; ++nt) {
    float4 v = {acc[nt][0] + bv[nt], acc[nt][1] + bv[nt], acc[nt][2] + bv[nt],
                acc[nt][3] + bv[nt]};
    int d = dh * 128 + nt * 16 + l15;
    *(float4*)(out + (size_t)b * 32768 + (size_t)d * 128 + kk0 + w * 16 + l4 * 4) = v;
  }
}

// ---------- launch ----------
extern "C" void kernel_launch(void* const* d_in, const int* in_sizes, int n_in,
                              void* d_out, int out_size, void* d_ws, size_t ws_size,
                              hipStream_t stream) {
  const float* c_in = (const float*)d_in[0];
  const float* x_in = (const float*)d_in[2];
  const float* Wih  = (const float*)d_in[3];
  const float* Whh  = (const float*)d_in[4];
  const float* bih  = (const float*)d_in[5];
  const float* bhh  = (const float*)d_in[6];
  const float* Wtok = (const float*)d_in[7];
  const float* btok = (const float*)d_in[8];
  const float* Wun  = (const float*)d_in[9];
  const float* bun  = (const float*)d_in[10];
  float* out = (float*)d_out;
  char* ws = (char*)d_ws;

  const size_t OW_HH = 0;                     // u16 packed [6144 frags][512]
  const size_t OW_C  = 6291456;               // u16 packed [1536 frags][512]
  const size_t OW_UN = 7864320;               // u16 packed [512 frags][512]
  const size_t OBC   = 8388608;               // f32 [3072]
  const size_t OXHI  = 8400896;               // u16 [128][65536]
  const size_t OXLO  = 25178112;
  const size_t OHHI  = 41955328;              // u16 [2][262144]
  const size_t OHLO  = 43003904;
  const size_t OYS   = 44052480;              // u16 packed [65536 frags][512]
  const size_t OBAR  = 111161344;             // u32 [256] barrier state
  const size_t NEED  = 111162368;
  if (ws_size < NEED) return;

  u16* whh_p = (u16*)(ws + OW_HH);
  u16* wc_p  = (u16*)(ws + OW_C);
  u16* wun_p = (u16*)(ws + OW_UN);
  float* bc  = (float*)(ws + OBC);
  u16* xhi   = (u16*)(ws + OXHI);
  u16* xlo   = (u16*)(ws + OXLO);
  u16* hhi   = (u16*)(ws + OHHI);
  u16* hlo   = (u16*)(ws + OHLO);
  u16* ys    = (u16*)(ws + OYS);
  unsigned* bar = (unsigned*)(ws + OBAR);

  k_round<<<1024, 256, 0, stream>>>(Whh, Wun, whh_p, wun_p);
  k_wcomb<<<dim3(48, 4), 256, 0, stream>>>(Wih, Wtok, wc_p);
  k_bcomb<<<3072, 256, 0, stream>>>(Wih, btok, bih, bc);
  k_xprep<<<1024, 256, 0, stream>>>(x_in, xhi, xlo);
  k_hinit<<<1024, 256, 0, stream>>>(c_in, hhi, hlo);
  k_zero<<<1, 256, 0, stream>>>(bar);

  {
    u16* hhi_l = hhi;
    u16* hlo_l = hlo;
    const u16* xhi_l = xhi;
    const u16* xlo_l = xlo;
    const u16* whp_l = whh_p;
    const u16* wcp_l = wc_p;
    const float* bih_l = bih;
    const float* bc_l = bc;
    const float* bhh_l = bhh;
    u16* ys_l = ys;
    unsigned* bar_l = bar;
    void* args[] = {&hhi_l, &hlo_l, &xhi_l, &xlo_l, &whp_l, &wcp_l,
                    &bih_l, &bc_l, &bhh_l, &ys_l, &bar_l};
    hipLaunchCooperativeKernel((const void*)k_gru2, dim3(256), dim3(512), args, 0, stream);
  }

  k_untok3<<<1024, 256, 0, stream>>>(ys, wun_p, bun, out);
}